// Round 3
// baseline (514.031 us; speedup 1.0000x reference)
//
#include <hip/hip_runtime.h>
#include <math.h>

#define D 128
#define ROWS 64     // rows per tile
#define PASSES 8    // 8 rows per pass x 8 passes = 64 rows, 256 threads

// e = exp(tanh(v)); tanh(v) = 1 - 2/(1+exp(2v)). Correct limits at +/-inf.
// src = tanh(.) in [-1,1] -> exp never overflows, so the reference's
// segment-max subtraction is a numerical no-op and is dropped.
__device__ __forceinline__ float fast_exp_tanh(float v) {
    float e2 = __expf(2.0f * v);
    float th = 1.0f - 2.0f * __builtin_amdgcn_rcpf(1.0f + e2);
    return __expf(th);
}

// Tile kernel: each block grid-strides over 64-row tiles.
// Step 1: 16 wave-loads issued up-front (deep MLP), x staged to LDS, 8
//         independent shfl-reduce chains -> e[row] (exp(tanh(dot))).
// Step 2: barrier.
// Step 3: threads 0..127 sweep the x-tile column-wise, flushing per-segment
//         weighted sums to global atomics at (uniform) segment boundaries.
__global__ __launch_bounds__(256) void attn_main(
    const float* __restrict__ x,
    const float* __restrict__ ref,
    const int*   __restrict__ index,
    const float* __restrict__ W,
    const float* __restrict__ b,
    float*       __restrict__ outnum,   // [B*D], pre-zeroed
    float*       __restrict__ den,      // [B],   pre-zeroed
    int N, int ntiles)
{
    __shared__ float x_tile[ROWS][D + 4];  // row stride 132 -> 2-way banks (free)
    __shared__ float e_arr[ROWS];
    __shared__ int   seg_arr[ROWS];

    const int tid  = threadIdx.x;
    const int prow = tid >> 5;   // row-within-pass 0..7
    const int cg   = tid & 31;   // column group (4 cols)

    const float4 wx = ((const float4*)W)[cg];        // W[0:128]
    const float4 wr = ((const float4*)(W + D))[cg];  // W[128:256]
    const float bias = b[0];

    for (int tile = blockIdx.x; tile < ntiles; tile += gridDim.x) {
        const int r0 = tile * ROWS;

        if (tid < ROWS) {
            int r = r0 + tid;
            seg_arr[tid] = (r < N) ? index[r] : -1;
        }

        // ---- step 1: all loads in flight, then 8 interleaved reduce chains
        float4 xv[PASSES], rv[PASSES];
        #pragma unroll
        for (int p = 0; p < PASSES; ++p) {
            int r  = r0 + p * 8 + prow;
            int rc = min(r, N - 1);            // clamp; e forced to 0 below
            const size_t off = (size_t)rc * D + cg * 4;
            xv[p] = *(const float4*)(x   + off);
            rv[p] = *(const float4*)(ref + off);
        }
        #pragma unroll
        for (int p = 0; p < PASSES; ++p) {
            const int row = p * 8 + prow;      // 0..63
            *(float4*)&x_tile[row][cg * 4] = xv[p];
            float partial = xv[p].x*wx.x + xv[p].y*wx.y + xv[p].z*wx.z + xv[p].w*wx.w
                          + rv[p].x*wr.x + rv[p].y*wr.y + rv[p].z*wr.z + rv[p].w*wr.w;
            #pragma unroll
            for (int off = 16; off >= 1; off >>= 1)
                partial += __shfl_xor(partial, off);   // within 32-lane half
            float e = fast_exp_tanh(partial + bias);
            if (cg == 0)
                e_arr[row] = ((r0 + row) < N) ? e : 0.f;
        }
        __syncthreads();

        // ---- step 3: per-dim weighted segment sums (index sorted ->
        //      boundary branch is wave-uniform; ~3 flushes per tile)
        if (tid < D) {
            const int d = tid;
            float accum = 0.f;
            int cs = seg_arr[0];
            #pragma unroll 8
            for (int r = 0; r < ROWS; ++r) {
                int s = seg_arr[r];
                if (s != cs) {
                    if (cs >= 0) atomicAdd(&outnum[(size_t)cs * D + d], accum);
                    accum = 0.f; cs = s;
                }
                accum += e_arr[r] * x_tile[r][d];
            }
            if (cs >= 0) atomicAdd(&outnum[(size_t)cs * D + d], accum);
        } else if (tid == 192) {   // one lane of wave 3: denominators
            float accum = 0.f;
            int cs = seg_arr[0];
            for (int r = 0; r < ROWS; ++r) {
                int s = seg_arr[r];
                if (s != cs) {
                    if (cs >= 0) atomicAdd(&den[cs], accum);
                    accum = 0.f; cs = s;
                }
                accum += e_arr[r];
            }
            if (cs >= 0) atomicAdd(&den[cs], accum);
        }
        __syncthreads();   // protect LDS reuse across tile iterations
    }
}

__global__ __launch_bounds__(256) void normalize_kernel(
    const float* __restrict__ outnum, const float* __restrict__ den,
    float* __restrict__ out, int total)
{
    int i = blockIdx.x * blockDim.x + threadIdx.x;
    if (i < total)
        out[i] = outnum[i] / (den[i >> 7] + 1e-16f);
}

extern "C" void kernel_launch(void* const* d_in, const int* in_sizes, int n_in,
                              void* d_out, int out_size, void* d_ws, size_t ws_size,
                              hipStream_t stream) {
    const float* x     = (const float*)d_in[0];
    const float* ref   = (const float*)d_in[1];
    const int*   index = (const int*)d_in[2];
    // d_in[3] = batch_size (device scalar; B derived from out_size instead)
    const float* W     = (const float*)d_in[4];
    const float* b     = (const float*)d_in[5];
    float* out = (float*)d_out;

    const int N = in_sizes[0] / D;
    const int B = out_size / D;
    const int ntiles = (N + ROWS - 1) / ROWS;

    float* outnum = (float*)d_ws;        // B*D accumulators
    float* den    = outnum + (size_t)B * D;  // B denominators

    hipMemsetAsync(outnum, 0, ((size_t)B * D + B) * sizeof(float), stream);
    attn_main<<<2048, 256, 0, stream>>>(x, ref, index, W, b, outnum, den, N, ntiles);
    normalize_kernel<<<(B * D + 255) / 256, 256, 0, stream>>>(outnum, den, out, B * D);
}